// Round 1
// baseline (125.602 us; speedup 1.0000x reference)
//
#include <hip/hip_runtime.h>
#include <math.h>

#define B    64
#define CTRL 512
#define KEY  64
#define MEMU 16384

__device__ __forceinline__ float softplusf(float x) {
    return x > 20.f ? x : log1pf(expf(x));
}

// ---------------- K1: per-batch head scalars -----------------------------
// Computes k = cs@key_W^T + key_b (64), beta, g, s0..s2 (softmax), y, |k|.
__global__ __launch_bounds__(256) void k1_scalars(
    const float* __restrict__ cs,
    const float* __restrict__ key_W, const float* __restrict__ key_b,
    const float* __restrict__ ks_W,  const float* __restrict__ ks_b,
    const float* __restrict__ ig_W,  const float* __restrict__ ig_b,
    const float* __restrict__ sw_W,  const float* __restrict__ sw_b,
    const float* __restrict__ sf_W,  const float* __restrict__ sf_b,
    float* __restrict__ ws_k, float* __restrict__ ws_scal)
{
    __shared__ float cs_s[CTRL];
    __shared__ float k_s[KEY];
    __shared__ float h_s[8];
    const int b = blockIdx.x;
    const int t = threadIdx.x;
    for (int i = t; i < CTRL; i += 256) cs_s[i] = cs[b * CTRL + i];
    __syncthreads();
    const int wave = t >> 6, lane = t & 63;
    for (int o = wave; o < 70; o += 4) {
        const float* W; float bias;
        if (o < 64)       { W = key_W + o * CTRL;      bias = key_b[o]; }
        else if (o == 64) { W = ks_W;                  bias = ks_b[0]; }
        else if (o == 65) { W = ig_W;                  bias = ig_b[0]; }
        else if (o < 69)  { W = sw_W + (o - 66) * CTRL; bias = sw_b[o - 66]; }
        else              { W = sf_W;                  bias = sf_b[0]; }
        float d = 0.f;
        for (int j = lane; j < CTRL; j += 64) d += cs_s[j] * W[j];
        #pragma unroll
        for (int off = 32; off >= 1; off >>= 1) d += __shfl_xor(d, off, 64);
        if (lane == 0) {
            float r = d + bias;
            if (o < 64) { k_s[o] = r; ws_k[b * KEY + o] = r; }
            else        h_s[o - 64] = r;
        }
    }
    __syncthreads();
    if (wave == 0) {
        float kv = k_s[lane];
        float sq = kv * kv;
        #pragma unroll
        for (int off = 32; off >= 1; off >>= 1) sq += __shfl_xor(sq, off, 64);
        if (lane == 0) {
            float knorm = sqrtf(sq);
            float beta = softplusf(h_s[0]);
            float g    = 1.f / (1.f + expf(-h_s[1]));
            float m3   = fmaxf(fmaxf(h_s[2], h_s[3]), h_s[4]);
            float e0 = expf(h_s[2] - m3), e1 = expf(h_s[3] - m3), e2 = expf(h_s[4] - m3);
            float inv3 = 1.f / (e0 + e1 + e2);
            float y = 1.f + softplusf(h_s[5]);
            float* sc = ws_scal + b * 8;
            sc[0] = beta; sc[1] = g;
            sc[2] = e0 * inv3; sc[3] = e1 * inv3; sc[4] = e2 * inv3;
            sc[5] = y; sc[6] = knorm;
        }
    }
}

// ---------------- K2: big pass 1 over memory ------------------------------
// e[b,m] = exp(beta*(dot/denom) - beta); per-block partial sums of e.
__global__ __launch_bounds__(256) void k2_scores(
    const float* __restrict__ mem,
    const float* __restrict__ ws_k, const float* __restrict__ ws_scal,
    float* __restrict__ ws_e, float* __restrict__ ws_pe)
{
    const int b = blockIdx.y;
    const int chunk = blockIdx.x;          // 0..15, 1024 rows each
    const int t = threadIdx.x;
    const float beta  = ws_scal[b * 8 + 0];
    const float knorm = ws_scal[b * 8 + 6];
    float kk[KEY];
    #pragma unroll
    for (int j = 0; j < KEY; ++j) kk[j] = ws_k[b * KEY + j];

    float esum = 0.f;
    #pragma unroll
    for (int i = 0; i < 4; ++i) {
        const int m = chunk * 1024 + i * 256 + t;
        const float4* rp = (const float4*)(mem + ((size_t)b * MEMU + m) * KEY);
        float dot = 0.f, sq = 0.f;
        #pragma unroll
        for (int q = 0; q < 16; ++q) {
            float4 v = rp[q];
            dot += v.x * kk[4*q+0] + v.y * kk[4*q+1] + v.z * kk[4*q+2] + v.w * kk[4*q+3];
            sq  += v.x * v.x + v.y * v.y + v.z * v.z + v.w * v.w;
        }
        const float denom = fmaxf(sqrtf(sq) * knorm, 1e-8f);
        const float e = expf(beta * (dot / denom) - beta);
        ws_e[b * MEMU + m] = e;
        esum += e;
    }
    __shared__ float red[4];
    #pragma unroll
    for (int off = 32; off >= 1; off >>= 1) esum += __shfl_xor(esum, off, 64);
    if ((t & 63) == 0) red[t >> 6] = esum;
    __syncthreads();
    if (t == 0) ws_pe[b * 16 + chunk] = red[0] + red[1] + red[2] + red[3];
}

// ---------------- K4: interpolate + circular shift + sharpen --------------
__global__ __launch_bounds__(256) void k4_sharp(
    const float* __restrict__ pw,
    const float* __restrict__ ws_e, const float* __restrict__ ws_pe,
    const float* __restrict__ ws_scal,
    float* __restrict__ ws_sharp, float* __restrict__ ws_ps)
{
    const int b = blockIdx.y, chunk = blockIdx.x, t = threadIdx.x;
    float sum_e = 0.f;
    #pragma unroll
    for (int i = 0; i < 16; ++i) sum_e += ws_pe[b * 16 + i];
    const float inv_e = 1.f / sum_e;
    const float g  = ws_scal[b*8+1];
    const float s0 = ws_scal[b*8+2], s1 = ws_scal[b*8+3], s2 = ws_scal[b*8+4];
    const float y  = ws_scal[b*8+5];
    const float cg = 1.f - g;
    const float* eb = ws_e + b * MEMU;
    const float* pb = pw   + b * MEMU;

    float ssum = 0.f;
    #pragma unroll
    for (int i = 0; i < 8; ++i) {
        const int m  = chunk * 2048 + i * 256 + t;
        const int mm = (m + MEMU - 1) & (MEMU - 1);
        const int mp = (m + 1) & (MEMU - 1);
        const float wim = g * eb[mm] * inv_e + cg * pb[mm];
        const float wi0 = g * eb[m ] * inv_e + cg * pb[m ];
        const float wip = g * eb[mp] * inv_e + cg * pb[mp];
        const float sh  = s0 * wim + s1 * wi0 + s2 * wip;
        const float sp  = expf(y * logf(sh));   // sh > 0 always
        ws_sharp[b * MEMU + m] = sp;
        ssum += sp;
    }
    __shared__ float red[4];
    #pragma unroll
    for (int off = 32; off >= 1; off >>= 1) ssum += __shfl_xor(ssum, off, 64);
    if ((t & 63) == 0) red[t >> 6] = ssum;
    __syncthreads();
    if (t == 0) ws_ps[b * 8 + chunk] = red[0] + red[1] + red[2] + red[3];
}

// ---------------- K6: normalize -> w (first output section) ---------------
__global__ __launch_bounds__(256) void k6_wout(
    const float* __restrict__ ws_sharp, const float* __restrict__ ws_ps,
    float* __restrict__ out)
{
    const int b = blockIdx.y, chunk = blockIdx.x, t = threadIdx.x;
    float ss = 0.f;
    #pragma unroll
    for (int i = 0; i < 8; ++i) ss += ws_ps[b * 8 + i];
    const float inv = 1.f / (ss + 1e-16f);
    #pragma unroll
    for (int i = 0; i < 8; ++i) {
        const int m = chunk * 2048 + i * 256 + t;
        out[b * MEMU + m] = ws_sharp[b * MEMU + m] * inv;
    }
}

// ---------------- K7: big pass 2 -- data partials --------------------------
__global__ __launch_bounds__(256) void k7_data(
    const float* __restrict__ mem, const float* __restrict__ out_w,
    float* __restrict__ ws_pd)
{
    const int b = blockIdx.y, chunk = blockIdx.x;   // 64 chunks x 256 rows
    const int t = threadIdx.x, wave = t >> 6, lane = t & 63;
    const int r0 = chunk * 256 + wave * 64;
    const float* wb = out_w + b * MEMU;
    const float* mb = mem + (size_t)b * MEMU * KEY;
    float acc = 0.f;
    #pragma unroll 4
    for (int i = 0; i < 64; ++i) {
        const int r = r0 + i;
        acc += wb[r] * mb[(size_t)r * KEY + lane];
    }
    __shared__ float red[4][64];
    red[wave][lane] = acc;
    __syncthreads();
    if (t < 64) {
        const float s = red[0][t] + red[1][t] + red[2][t] + red[3][t];
        ws_pd[(b * 64 + chunk) * 64 + t] = s;
    }
}

// ---------------- K8: reduce data partials -> second output section --------
__global__ __launch_bounds__(64) void k8_reduce(
    const float* __restrict__ ws_pd, float* __restrict__ out)
{
    const int b = blockIdx.x, j = threadIdx.x;
    float s = 0.f;
    #pragma unroll 8
    for (int c = 0; c < 64; ++c) s += ws_pd[(b * 64 + c) * 64 + j];
    out[(size_t)B * MEMU + b * KEY + j] = s;
}

extern "C" void kernel_launch(void* const* d_in, const int* in_sizes, int n_in,
                              void* d_out, int out_size, void* d_ws, size_t ws_size,
                              hipStream_t stream) {
    (void)in_sizes; (void)n_in; (void)out_size; (void)ws_size;
    const float* cs    = (const float*)d_in[0];
    const float* pw    = (const float*)d_in[1];
    const float* mem   = (const float*)d_in[2];
    const float* key_W = (const float*)d_in[3];
    const float* key_b = (const float*)d_in[4];
    const float* ks_W  = (const float*)d_in[5];
    const float* ks_b  = (const float*)d_in[6];
    const float* ig_W  = (const float*)d_in[7];
    const float* ig_b  = (const float*)d_in[8];
    const float* sw_W  = (const float*)d_in[9];
    const float* sw_b  = (const float*)d_in[10];
    const float* sf_W  = (const float*)d_in[11];
    const float* sf_b  = (const float*)d_in[12];
    // d_in[13], d_in[14] (wd_W, wd_b) unused by the reference head.
    float* out = (float*)d_out;
    float* ws  = (float*)d_ws;

    // workspace layout (floats)
    float* ws_k     = ws;                      // 64*64
    float* ws_scal  = ws_k + B * KEY;          // 64*8
    float* ws_e     = ws_scal + B * 8;         // 64*16384
    float* ws_sharp = ws_e + (size_t)B * MEMU; // 64*16384
    float* ws_pe    = ws_sharp + (size_t)B * MEMU; // 64*16
    float* ws_ps    = ws_pe + B * 16;          // 64*8
    float* ws_pd    = ws_ps + B * 8;           // 64*64*64

    k1_scalars<<<dim3(B), dim3(256), 0, stream>>>(cs, key_W, key_b, ks_W, ks_b,
                                                  ig_W, ig_b, sw_W, sw_b, sf_W, sf_b,
                                                  ws_k, ws_scal);
    k2_scores<<<dim3(16, B), dim3(256), 0, stream>>>(mem, ws_k, ws_scal, ws_e, ws_pe);
    k4_sharp<<<dim3(8, B), dim3(256), 0, stream>>>(pw, ws_e, ws_pe, ws_scal, ws_sharp, ws_ps);
    k6_wout<<<dim3(8, B), dim3(256), 0, stream>>>(ws_sharp, ws_ps, out);
    k7_data<<<dim3(64, B), dim3(256), 0, stream>>>(mem, out, ws_pd);
    k8_reduce<<<dim3(B), dim3(64), 0, stream>>>(ws_pd, out);
}

// Round 2
// 120.686 us; speedup vs baseline: 1.0407x; 1.0407x over previous
//
#include <hip/hip_runtime.h>
#include <math.h>

#define B    64
#define CTRL 512
#define KEY  64
#define MEMU 16384

__device__ __forceinline__ float softplusf(float x) {
    return x > 20.f ? x : log1pf(expf(x));
}

// ---------------- K1: per-batch head scalars -----------------------------
__global__ __launch_bounds__(256) void k1_scalars(
    const float* __restrict__ cs,
    const float* __restrict__ key_W, const float* __restrict__ key_b,
    const float* __restrict__ ks_W,  const float* __restrict__ ks_b,
    const float* __restrict__ ig_W,  const float* __restrict__ ig_b,
    const float* __restrict__ sw_W,  const float* __restrict__ sw_b,
    const float* __restrict__ sf_W,  const float* __restrict__ sf_b,
    float* __restrict__ ws_k, float* __restrict__ ws_scal)
{
    __shared__ float cs_s[CTRL];
    __shared__ float k_s[KEY];
    __shared__ float h_s[8];
    const int b = blockIdx.x;
    const int t = threadIdx.x;
    for (int i = t; i < CTRL; i += 256) cs_s[i] = cs[b * CTRL + i];
    __syncthreads();
    const int wave = t >> 6, lane = t & 63;
    for (int o = wave; o < 70; o += 4) {
        const float* W; float bias;
        if (o < 64)       { W = key_W + o * CTRL;      bias = key_b[o]; }
        else if (o == 64) { W = ks_W;                  bias = ks_b[0]; }
        else if (o == 65) { W = ig_W;                  bias = ig_b[0]; }
        else if (o < 69)  { W = sw_W + (o - 66) * CTRL; bias = sw_b[o - 66]; }
        else              { W = sf_W;                  bias = sf_b[0]; }
        float d = 0.f;
        for (int j = lane; j < CTRL; j += 64) d += cs_s[j] * W[j];
        #pragma unroll
        for (int off = 32; off >= 1; off >>= 1) d += __shfl_xor(d, off, 64);
        if (lane == 0) {
            float r = d + bias;
            if (o < 64) { k_s[o] = r; ws_k[b * KEY + o] = r; }
            else        h_s[o - 64] = r;
        }
    }
    __syncthreads();
    if (wave == 0) {
        float kv = k_s[lane];
        float sq = kv * kv;
        #pragma unroll
        for (int off = 32; off >= 1; off >>= 1) sq += __shfl_xor(sq, off, 64);
        if (lane == 0) {
            float knorm = sqrtf(sq);
            float beta = softplusf(h_s[0]);
            float g    = 1.f / (1.f + expf(-h_s[1]));
            float m3   = fmaxf(fmaxf(h_s[2], h_s[3]), h_s[4]);
            float e0 = expf(h_s[2] - m3), e1 = expf(h_s[3] - m3), e2 = expf(h_s[4] - m3);
            float inv3 = 1.f / (e0 + e1 + e2);
            float y = 1.f + softplusf(h_s[5]);
            float* sc = ws_scal + b * 8;
            sc[0] = beta; sc[1] = g;
            sc[2] = e0 * inv3; sc[3] = e1 * inv3; sc[4] = e2 * inv3;
            sc[5] = y; sc[6] = knorm;
        }
    }
}

// ---------------- K2: big pass 1 over memory ------------------------------
// e[b,m] = exp(beta*(dot/denom) - beta); per-block partial sums of e.
__global__ __launch_bounds__(256) void k2_scores(
    const float* __restrict__ mem,
    const float* __restrict__ ws_k, const float* __restrict__ ws_scal,
    float* __restrict__ ws_e, float* __restrict__ ws_pe)
{
    const int b = blockIdx.y;
    const int chunk = blockIdx.x;          // 0..15, 1024 rows each
    const int t = threadIdx.x;
    const float beta  = ws_scal[b * 8 + 0];
    const float knorm = ws_scal[b * 8 + 6];
    float kk[KEY];
    #pragma unroll
    for (int j = 0; j < KEY; ++j) kk[j] = ws_k[b * KEY + j];

    float esum = 0.f;
    #pragma unroll
    for (int i = 0; i < 4; ++i) {
        const int m = chunk * 1024 + i * 256 + t;
        const float4* rp = (const float4*)(mem + ((size_t)b * MEMU + m) * KEY);
        float dot = 0.f, sq = 0.f;
        #pragma unroll
        for (int q = 0; q < 16; ++q) {
            float4 v = rp[q];
            dot += v.x * kk[4*q+0] + v.y * kk[4*q+1] + v.z * kk[4*q+2] + v.w * kk[4*q+3];
            sq  += v.x * v.x + v.y * v.y + v.z * v.z + v.w * v.w;
        }
        const float denom = fmaxf(sqrtf(sq) * knorm, 1e-8f);
        const float e = expf(beta * (dot / denom) - beta);
        ws_e[b * MEMU + m] = e;
        esum += e;
    }
    __shared__ float red[4];
    #pragma unroll
    for (int off = 32; off >= 1; off >>= 1) esum += __shfl_xor(esum, off, 64);
    if ((t & 63) == 0) red[t >> 6] = esum;
    __syncthreads();
    if (t == 0) ws_pe[b * 16 + chunk] = red[0] + red[1] + red[2] + red[3];
}

// ---------------- K4: interpolate + circular shift + sharpen --------------
__global__ __launch_bounds__(256) void k4_sharp(
    const float* __restrict__ pw,
    const float* __restrict__ ws_e, const float* __restrict__ ws_pe,
    const float* __restrict__ ws_scal,
    float* __restrict__ ws_sharp, float* __restrict__ ws_ps)
{
    const int b = blockIdx.y, chunk = blockIdx.x, t = threadIdx.x;
    float sum_e = 0.f;
    #pragma unroll
    for (int i = 0; i < 16; ++i) sum_e += ws_pe[b * 16 + i];
    const float inv_e = 1.f / sum_e;
    const float g  = ws_scal[b*8+1];
    const float s0 = ws_scal[b*8+2], s1 = ws_scal[b*8+3], s2 = ws_scal[b*8+4];
    const float y  = ws_scal[b*8+5];
    const float cg = 1.f - g;
    const float* eb = ws_e + b * MEMU;
    const float* pb = pw   + b * MEMU;

    float ssum = 0.f;
    #pragma unroll
    for (int i = 0; i < 8; ++i) {
        const int m  = chunk * 2048 + i * 256 + t;
        const int mm = (m + MEMU - 1) & (MEMU - 1);
        const int mp = (m + 1) & (MEMU - 1);
        const float wim = g * eb[mm] * inv_e + cg * pb[mm];
        const float wi0 = g * eb[m ] * inv_e + cg * pb[m ];
        const float wip = g * eb[mp] * inv_e + cg * pb[mp];
        const float sh  = s0 * wim + s1 * wi0 + s2 * wip;
        const float sp  = expf(y * logf(sh));   // sh > 0 always
        ws_sharp[b * MEMU + m] = sp;
        ssum += sp;
    }
    __shared__ float red[4];
    #pragma unroll
    for (int off = 32; off >= 1; off >>= 1) ssum += __shfl_xor(ssum, off, 64);
    if ((t & 63) == 0) red[t >> 6] = ssum;
    __syncthreads();
    if (t == 0) ws_ps[b * 8 + chunk] = red[0] + red[1] + red[2] + red[3];
}

// ---------------- K7: fused normalize + w-out + data partials --------------
// Each block: 256 rows of one batch. Computes w = sharp*inv, writes w to
// d_out, and accumulates data partials with 16B/lane contiguous mem loads
// (wave covers 4 consecutive rows = 1KB per instruction).
__global__ __launch_bounds__(256) void k7_data(
    const float* __restrict__ mem,
    const float* __restrict__ ws_sharp, const float* __restrict__ ws_ps,
    float* __restrict__ out_w, float* __restrict__ ws_pd)
{
    const int b = blockIdx.y, chunk = blockIdx.x;   // 64 chunks x 256 rows
    const int t = threadIdx.x, wv = t >> 6, lane = t & 63;
    __shared__ float w_lds[256];
    __shared__ float red[4][64];

    float ss = 0.f;
    #pragma unroll
    for (int i = 0; i < 8; ++i) ss += ws_ps[b * 8 + i];
    const float inv = 1.f / (ss + 1e-16f);

    const int m0 = chunk * 256;
    const float wval = ws_sharp[b * MEMU + m0 + t] * inv;
    out_w[b * MEMU + m0 + t] = wval;
    w_lds[t] = wval;
    __syncthreads();

    // wave wv handles local rows [wv*64, wv*64+64); 4 rows per step.
    const float* mb = mem + ((size_t)b * MEMU + m0 + wv * 64) * KEY;
    const int rsub = lane >> 4;          // 0..3: which of the 4 rows
    const int c4   = (lane & 15) * 4;    // column base (float4)
    float4 acc = make_float4(0.f, 0.f, 0.f, 0.f);
    #pragma unroll
    for (int s = 0; s < 16; ++s) {
        const int r = s * 4 + rsub;
        const float4 v = *(const float4*)(mb + (size_t)r * KEY + c4);
        const float wr = w_lds[wv * 64 + r];
        acc.x += wr * v.x; acc.y += wr * v.y; acc.z += wr * v.z; acc.w += wr * v.w;
    }
    // merge the 4 row-groups (lanes differing in bits 4,5)
    #pragma unroll
    for (int off = 16; off <= 32; off <<= 1) {
        acc.x += __shfl_xor(acc.x, off, 64);
        acc.y += __shfl_xor(acc.y, off, 64);
        acc.z += __shfl_xor(acc.z, off, 64);
        acc.w += __shfl_xor(acc.w, off, 64);
    }
    if (lane < 16) {
        red[wv][c4 + 0] = acc.x; red[wv][c4 + 1] = acc.y;
        red[wv][c4 + 2] = acc.z; red[wv][c4 + 3] = acc.w;
    }
    __syncthreads();
    if (t < 64) {
        ws_pd[(b * 64 + chunk) * 64 + t] =
            red[0][t] + red[1][t] + red[2][t] + red[3][t];
    }
}

// ---------------- K8: reduce data partials -> second output section --------
__global__ __launch_bounds__(64) void k8_reduce(
    const float* __restrict__ ws_pd, float* __restrict__ out)
{
    const int b = blockIdx.x, j = threadIdx.x;
    float s = 0.f;
    #pragma unroll 8
    for (int c = 0; c < 64; ++c) s += ws_pd[(b * 64 + c) * 64 + j];
    out[(size_t)B * MEMU + b * KEY + j] = s;
}

extern "C" void kernel_launch(void* const* d_in, const int* in_sizes, int n_in,
                              void* d_out, int out_size, void* d_ws, size_t ws_size,
                              hipStream_t stream) {
    (void)in_sizes; (void)n_in; (void)out_size; (void)ws_size;
    const float* cs    = (const float*)d_in[0];
    const float* pw    = (const float*)d_in[1];
    const float* mem   = (const float*)d_in[2];
    const float* key_W = (const float*)d_in[3];
    const float* key_b = (const float*)d_in[4];
    const float* ks_W  = (const float*)d_in[5];
    const float* ks_b  = (const float*)d_in[6];
    const float* ig_W  = (const float*)d_in[7];
    const float* ig_b  = (const float*)d_in[8];
    const float* sw_W  = (const float*)d_in[9];
    const float* sw_b  = (const float*)d_in[10];
    const float* sf_W  = (const float*)d_in[11];
    const float* sf_b  = (const float*)d_in[12];
    float* out = (float*)d_out;
    float* ws  = (float*)d_ws;

    // workspace layout (floats)
    float* ws_k     = ws;                          // 64*64
    float* ws_scal  = ws_k + B * KEY;              // 64*8
    float* ws_e     = ws_scal + B * 8;             // 64*16384
    float* ws_sharp = ws_e + (size_t)B * MEMU;     // 64*16384
    float* ws_pe    = ws_sharp + (size_t)B * MEMU; // 64*16
    float* ws_ps    = ws_pe + B * 16;              // 64*8
    float* ws_pd    = ws_ps + B * 8;               // 64*64*64

    k1_scalars<<<dim3(B), dim3(256), 0, stream>>>(cs, key_W, key_b, ks_W, ks_b,
                                                  ig_W, ig_b, sw_W, sw_b, sf_W, sf_b,
                                                  ws_k, ws_scal);
    k2_scores<<<dim3(16, B), dim3(256), 0, stream>>>(mem, ws_k, ws_scal, ws_e, ws_pe);
    k4_sharp<<<dim3(8, B), dim3(256), 0, stream>>>(pw, ws_e, ws_pe, ws_scal, ws_sharp, ws_ps);
    k7_data<<<dim3(64, B), dim3(256), 0, stream>>>(mem, ws_sharp, ws_ps, out, ws_pd);
    k8_reduce<<<dim3(B), dim3(64), 0, stream>>>(ws_pd, out);
}

// Round 3
// 118.879 us; speedup vs baseline: 1.0566x; 1.0152x over previous
//
#include <hip/hip_runtime.h>
#include <math.h>

#define B    64
#define CTRL 512
#define KEY  64
#define MEMU 16384

__device__ __forceinline__ float softplusf(float x) {
    return x > 20.f ? x : log1pf(expf(x));
}

// ---------------- K1: per-batch head scalars -----------------------------
__global__ __launch_bounds__(256) void k1_scalars(
    const float* __restrict__ cs,
    const float* __restrict__ key_W, const float* __restrict__ key_b,
    const float* __restrict__ ks_W,  const float* __restrict__ ks_b,
    const float* __restrict__ ig_W,  const float* __restrict__ ig_b,
    const float* __restrict__ sw_W,  const float* __restrict__ sw_b,
    const float* __restrict__ sf_W,  const float* __restrict__ sf_b,
    float* __restrict__ ws_k, float* __restrict__ ws_scal)
{
    __shared__ float cs_s[CTRL];
    __shared__ float k_s[KEY];
    __shared__ float h_s[8];
    const int b = blockIdx.x;
    const int t = threadIdx.x;
    for (int i = t; i < CTRL; i += 256) cs_s[i] = cs[b * CTRL + i];
    __syncthreads();
    const int wave = t >> 6, lane = t & 63;
    for (int o = wave; o < 70; o += 4) {
        const float* W; float bias;
        if (o < 64)       { W = key_W + o * CTRL;      bias = key_b[o]; }
        else if (o == 64) { W = ks_W;                  bias = ks_b[0]; }
        else if (o == 65) { W = ig_W;                  bias = ig_b[0]; }
        else if (o < 69)  { W = sw_W + (o - 66) * CTRL; bias = sw_b[o - 66]; }
        else              { W = sf_W;                  bias = sf_b[0]; }
        float d = 0.f;
        for (int j = lane; j < CTRL; j += 64) d += cs_s[j] * W[j];
        #pragma unroll
        for (int off = 32; off >= 1; off >>= 1) d += __shfl_xor(d, off, 64);
        if (lane == 0) {
            float r = d + bias;
            if (o < 64) { k_s[o] = r; ws_k[b * KEY + o] = r; }
            else        h_s[o - 64] = r;
        }
    }
    __syncthreads();
    if (wave == 0) {
        float kv = k_s[lane];
        float sq = kv * kv;
        #pragma unroll
        for (int off = 32; off >= 1; off >>= 1) sq += __shfl_xor(sq, off, 64);
        if (lane == 0) {
            float knorm = sqrtf(sq);
            float beta = softplusf(h_s[0]);
            float g    = 1.f / (1.f + expf(-h_s[1]));
            float m3   = fmaxf(fmaxf(h_s[2], h_s[3]), h_s[4]);
            float e0 = expf(h_s[2] - m3), e1 = expf(h_s[3] - m3), e2 = expf(h_s[4] - m3);
            float inv3 = 1.f / (e0 + e1 + e2);
            float y = 1.f + softplusf(h_s[5]);
            float* sc = ws_scal + b * 8;
            sc[0] = beta; sc[1] = g;
            sc[2] = e0 * inv3; sc[3] = e1 * inv3; sc[4] = e2 * inv3;
            sc[5] = y; sc[6] = knorm;
        }
    }
}

// ---------------- K2: big pass 1 over memory (FORWARD order) --------------
// e[b,m] = exp(beta*(dot/denom) - beta); per-block partial sums of e.
__global__ __launch_bounds__(256) void k2_scores(
    const float* __restrict__ mem,
    const float* __restrict__ ws_k, const float* __restrict__ ws_scal,
    float* __restrict__ ws_e, float* __restrict__ ws_pe)
{
    const int b = blockIdx.y;
    const int chunk = blockIdx.x;          // 0..15, 1024 rows each
    const int t = threadIdx.x;
    const float beta  = ws_scal[b * 8 + 0];
    const float knorm = ws_scal[b * 8 + 6];
    float kk[KEY];
    #pragma unroll
    for (int j = 0; j < KEY; ++j) kk[j] = ws_k[b * KEY + j];

    float esum = 0.f;
    #pragma unroll
    for (int i = 0; i < 4; ++i) {
        const int m = chunk * 1024 + i * 256 + t;
        const float4* rp = (const float4*)(mem + ((size_t)b * MEMU + m) * KEY);
        float dot = 0.f, sq = 0.f;
        #pragma unroll
        for (int q = 0; q < 16; ++q) {
            float4 v = rp[q];
            dot += v.x * kk[4*q+0] + v.y * kk[4*q+1] + v.z * kk[4*q+2] + v.w * kk[4*q+3];
            sq  += v.x * v.x + v.y * v.y + v.z * v.z + v.w * v.w;
        }
        const float denom = fmaxf(sqrtf(sq) * knorm, 1e-8f);
        const float e = expf(beta * (dot / denom) - beta);
        ws_e[b * MEMU + m] = e;
        esum += e;
    }
    __shared__ float red[4];
    #pragma unroll
    for (int off = 32; off >= 1; off >>= 1) esum += __shfl_xor(esum, off, 64);
    if ((t & 63) == 0) red[t >> 6] = esum;
    __syncthreads();
    if (t == 0) ws_pe[b * 16 + chunk] = red[0] + red[1] + red[2] + red[3];
}

// ---------------- K4: interpolate + circular shift + sharpen --------------
__global__ __launch_bounds__(256) void k4_sharp(
    const float* __restrict__ pw,
    const float* __restrict__ ws_e, const float* __restrict__ ws_pe,
    const float* __restrict__ ws_scal,
    float* __restrict__ ws_sharp, float* __restrict__ ws_ps)
{
    const int b = blockIdx.y, chunk = blockIdx.x, t = threadIdx.x;
    float sum_e = 0.f;
    #pragma unroll
    for (int i = 0; i < 16; ++i) sum_e += ws_pe[b * 16 + i];
    const float inv_e = 1.f / sum_e;
    const float g  = ws_scal[b*8+1];
    const float s0 = ws_scal[b*8+2], s1 = ws_scal[b*8+3], s2 = ws_scal[b*8+4];
    const float y  = ws_scal[b*8+5];
    const float cg = 1.f - g;
    const float* eb = ws_e + b * MEMU;
    const float* pb = pw   + b * MEMU;

    float ssum = 0.f;
    #pragma unroll
    for (int i = 0; i < 8; ++i) {
        const int m  = chunk * 2048 + i * 256 + t;
        const int mm = (m + MEMU - 1) & (MEMU - 1);
        const int mp = (m + 1) & (MEMU - 1);
        const float wim = g * eb[mm] * inv_e + cg * pb[mm];
        const float wi0 = g * eb[m ] * inv_e + cg * pb[m ];
        const float wip = g * eb[mp] * inv_e + cg * pb[mp];
        const float sh  = s0 * wim + s1 * wi0 + s2 * wip;
        const float sp  = expf(y * logf(sh));   // sh > 0 always
        ws_sharp[b * MEMU + m] = sp;
        ssum += sp;
    }
    __shared__ float red[4];
    #pragma unroll
    for (int off = 32; off >= 1; off >>= 1) ssum += __shfl_xor(ssum, off, 64);
    if ((t & 63) == 0) red[t >> 6] = ssum;
    __syncthreads();
    if (t == 0) ws_ps[b * 8 + chunk] = red[0] + red[1] + red[2] + red[3];
}

// ---------------- K7: fused normalize + w-out + data partials --------------
// REVERSE traversal: first blocks touch the END of mem, which K2 just left
// hot in the 256MB Infinity Cache (mem is 268MB). Steady-state graph replays
// ping-pong: K2-forward finds the head hot from K7's reverse pass.
__global__ __launch_bounds__(256) void k7_data(
    const float* __restrict__ mem,
    const float* __restrict__ ws_sharp, const float* __restrict__ ws_ps,
    float* __restrict__ out_w, float* __restrict__ ws_pd)
{
    const int b     = (B - 1) - blockIdx.y;      // reverse batch order
    const int chunk = 63 - blockIdx.x;           // reverse chunk order
    const int t = threadIdx.x, wv = t >> 6, lane = t & 63;
    __shared__ float w_lds[256];
    __shared__ float red[4][64];

    float ss = 0.f;
    #pragma unroll
    for (int i = 0; i < 8; ++i) ss += ws_ps[b * 8 + i];
    const float inv = 1.f / (ss + 1e-16f);

    const int m0 = chunk * 256;
    const float wval = ws_sharp[b * MEMU + m0 + t] * inv;
    __builtin_nontemporal_store(wval, &out_w[b * MEMU + m0 + t]); // w never re-read on device
    w_lds[t] = wval;
    __syncthreads();

    // wave wv handles local rows [wv*64, wv*64+64); 4 rows per step, 16B/lane.
    const float* mb = mem + ((size_t)b * MEMU + m0 + wv * 64) * KEY;
    const int rsub = lane >> 4;          // 0..3: which of the 4 rows
    const int c4   = (lane & 15) * 4;    // column base (float4)
    float4 acc = make_float4(0.f, 0.f, 0.f, 0.f);
    #pragma unroll
    for (int s = 0; s < 16; ++s) {
        const int r = s * 4 + rsub;
        const float4 v = *(const float4*)(mb + (size_t)r * KEY + c4);
        const float wr = w_lds[wv * 64 + r];
        acc.x += wr * v.x; acc.y += wr * v.y; acc.z += wr * v.z; acc.w += wr * v.w;
    }
    #pragma unroll
    for (int off = 16; off <= 32; off <<= 1) {
        acc.x += __shfl_xor(acc.x, off, 64);
        acc.y += __shfl_xor(acc.y, off, 64);
        acc.z += __shfl_xor(acc.z, off, 64);
        acc.w += __shfl_xor(acc.w, off, 64);
    }
    if (lane < 16) {
        red[wv][c4 + 0] = acc.x; red[wv][c4 + 1] = acc.y;
        red[wv][c4 + 2] = acc.z; red[wv][c4 + 3] = acc.w;
    }
    __syncthreads();
    if (t < 64) {
        ws_pd[(b * 64 + chunk) * 64 + t] =
            red[0][t] + red[1][t] + red[2][t] + red[3][t];
    }
}

// ---------------- K8: reduce data partials -> second output section --------
__global__ __launch_bounds__(64) void k8_reduce(
    const float* __restrict__ ws_pd, float* __restrict__ out)
{
    const int b = blockIdx.x, j = threadIdx.x;
    float s = 0.f;
    #pragma unroll 8
    for (int c = 0; c < 64; ++c) s += ws_pd[(b * 64 + c) * 64 + j];
    out[(size_t)B * MEMU + b * KEY + j] = s;
}

extern "C" void kernel_launch(void* const* d_in, const int* in_sizes, int n_in,
                              void* d_out, int out_size, void* d_ws, size_t ws_size,
                              hipStream_t stream) {
    (void)in_sizes; (void)n_in; (void)out_size; (void)ws_size;
    const float* cs    = (const float*)d_in[0];
    const float* pw    = (const float*)d_in[1];
    const float* mem   = (const float*)d_in[2];
    const float* key_W = (const float*)d_in[3];
    const float* key_b = (const float*)d_in[4];
    const float* ks_W  = (const float*)d_in[5];
    const float* ks_b  = (const float*)d_in[6];
    const float* ig_W  = (const float*)d_in[7];
    const float* ig_b  = (const float*)d_in[8];
    const float* sw_W  = (const float*)d_in[9];
    const float* sw_b  = (const float*)d_in[10];
    const float* sf_W  = (const float*)d_in[11];
    const float* sf_b  = (const float*)d_in[12];
    float* out = (float*)d_out;
    float* ws  = (float*)d_ws;

    // workspace layout (floats)
    float* ws_k     = ws;                          // 64*64
    float* ws_scal  = ws_k + B * KEY;              // 64*8
    float* ws_e     = ws_scal + B * 8;             // 64*16384
    float* ws_sharp = ws_e + (size_t)B * MEMU;     // 64*16384
    float* ws_pe    = ws_sharp + (size_t)B * MEMU; // 64*16
    float* ws_ps    = ws_pe + B * 16;              // 64*8
    float* ws_pd    = ws_ps + B * 8;               // 64*64*64

    k1_scalars<<<dim3(B), dim3(256), 0, stream>>>(cs, key_W, key_b, ks_W, ks_b,
                                                  ig_W, ig_b, sw_W, sw_b, sf_W, sf_b,
                                                  ws_k, ws_scal);
    k2_scores<<<dim3(16, B), dim3(256), 0, stream>>>(mem, ws_k, ws_scal, ws_e, ws_pe);
    k4_sharp<<<dim3(8, B), dim3(256), 0, stream>>>(pw, ws_e, ws_pe, ws_scal, ws_sharp, ws_ps);
    k7_data<<<dim3(64, B), dim3(256), 0, stream>>>(mem, ws_sharp, ws_ps, out, ws_pd);
    k8_reduce<<<dim3(B), dim3(64), 0, stream>>>(ws_pd, out);
}